// Round 6
// baseline (496.118 us; speedup 1.0000x reference)
//
#include <hip/hip_runtime.h>

typedef short s16x8 __attribute__((ext_vector_type(8)));
typedef float f32x4 __attribute__((ext_vector_type(4)));

#define MFMA16(a, b, c) __builtin_amdgcn_mfma_f32_16x16x32_bf16((a), (b), (c), 0, 0, 0)

__device__ __forceinline__ unsigned short f2b(float f) {
  union { float f; unsigned int u; } v; v.f = f;
  unsigned int u = v.u;
  unsigned int r = (u + 0x7fffu + ((u >> 16) & 1u)) >> 16;  // RNE
  return (unsigned short)r;
}
__device__ __forceinline__ float b2f(unsigned short b) {
  union { unsigned int u; float f; } v; v.u = ((unsigned int)b) << 16;
  return v.f;
}

// ---------------- prep ----------------
__global__ __launch_bounds__(256) void cvt_x(const float* __restrict__ x,
                                             unsigned short* __restrict__ xb) {
  size_t i = ((size_t)blockIdx.x * 256 + threadIdx.x) * 4;
  float4 v = *(const float4*)(x + i);
  ushort4 o;
  o.x = f2b(v.x); o.y = f2b(v.y); o.z = f2b(v.z); o.w = f2b(v.w);
  *(ushort4*)(xb + i) = o;
}

// WcatT[n][k] = W[k][n], n in [0,3072): [wq | wkv | hq | hkv]
__global__ __launch_bounds__(256) void build_wt(const float* __restrict__ wq,
                                                const float* __restrict__ wkv,
                                                const float* __restrict__ hq,
                                                const float* __restrict__ hkv,
                                                unsigned short* __restrict__ WT) {
  const int n = blockIdx.x, k = threadIdx.x;
  float v;
  if (n < 512)       v = wq [(size_t)k * 512  + n];
  else if (n < 1536) v = wkv[(size_t)k * 1024 + (n - 512)];
  else if (n < 2048) v = hq [(size_t)k * 512  + (n - 1536)];
  else               v = hkv[(size_t)k * 1024 + (n - 2048)];
  WT[(size_t)n * 256 + k] = f2b(v);
}

// W2T[n][k] = [wout;hout][k][n], n<256, k<1024
__global__ __launch_bounds__(256) void build_w2t(const float* __restrict__ wout,
                                                 const float* __restrict__ hout,
                                                 unsigned short* __restrict__ W2T) {
  const int n = blockIdx.x;
  for (int k = threadIdx.x; k < 1024; k += 256) {
    const float v = (k < 512) ? wout[(size_t)k * 256 + n] : hout[(size_t)(k - 512) * 256 + n];
    W2T[(size_t)n * 1024 + k] = f2b(v);
  }
}

// ---------------- QKV projection, direct global->VGPR (no LDS, no barriers) ----------------
// Block = 64 m-rows x 256 n-cols; 4 waves, each a 64x64 wave-tile.
// All waves read the same A rows (L1 broadcast); W is L2-resident (0.79 MB/branch).
// Fully-unrolled K loop (8 steps): compiler hoists next-step loads under MFMAs.
// MFMA operands SWAPPED: lane holds 4 consecutive n for fixed m -> ushort4 stores.
// C layout (per part q/k/v of 16777216 elems):
//   branch 0 (col attn): part + ((w*8+H)*128 + h)*64 + d     (slab = 128x64)
//   branch 1 (row attn): part + ((r*8+H)*256 + i)*64 + d     (slab = 256x64)
__global__ __launch_bounds__(256) void gemm_qkv(const unsigned short* __restrict__ X,
                                                const unsigned short* __restrict__ WT,
                                                unsigned short* __restrict__ C,
                                                int branch) {
  const int tid = threadIdx.x, wave = tid >> 6, lane = tid & 63;
  const int q = lane >> 4, l = lane & 15;
  const int m0 = blockIdx.x * 64;
  const int nw = blockIdx.y * 256 + wave * 64;
  f32x4 acc[4][4] = {};
#pragma unroll
  for (int ks = 0; ks < 8; ++ks) {
    const int kk = ks * 32 + q * 8;
    s16x8 a[4], b[4];
#pragma unroll
    for (int i = 0; i < 4; ++i)
      a[i] = *(const s16x8*)(X + (size_t)(m0 + i * 16 + l) * 256 + kk);
#pragma unroll
    for (int j = 0; j < 4; ++j)
      b[j] = *(const s16x8*)(WT + (size_t)(nw + j * 16 + l) * 256 + kk);
#pragma unroll
    for (int i = 0; i < 4; ++i)
#pragma unroll
      for (int j = 0; j < 4; ++j) acc[i][j] = MFMA16(b[j], a[i], acc[i][j]);  // swapped: D^T
  }
  // epilogue: lane (q,l) frag (i,j) holds m = m0+i*16+l, n = nw+j*16+q*4 .. +3
#pragma unroll
  for (int i = 0; i < 4; ++i) {
    const int m = m0 + i * 16 + l;
    const int mrow = (branch == 0) ? ((m & 255) * 8) : ((m >> 8) * 8);
    const int mcol = (branch == 0) ? (m >> 8) : (m & 255);
    const int mdim = (branch == 0) ? 128 : 256;
#pragma unroll
    for (int j = 0; j < 4; ++j) {
      const int n = nw + j * 16 + q * 4;
      const int part = n >> 9, H = (n & 511) >> 6, d = n & 63;
      ushort4 o;
      o.x = f2b(acc[i][j][0]); o.y = f2b(acc[i][j][1]);
      o.z = f2b(acc[i][j][2]); o.w = f2b(acc[i][j][3]);
      unsigned short* base = C + (size_t)part * 16777216;
      const size_t idx = ((size_t)(mrow + H) * mdim + mcol) * 64 + d;
      *(ushort4*)(base + idx) = o;
    }
  }
}

// ---------------- column attention: one block per (w, H) ----------------
// In-register softmax: after QK^T the 16 lanes sharing q hold the same row,
// so row-reduce = 7 in-register ops over j + shfl_xor butterfly over l-bits.
__global__ __launch_bounds__(256) void col_attn(const unsigned short* __restrict__ C,
                                                unsigned short* __restrict__ O) {
  __shared__ unsigned short Sp[128 * 136];  // normalized P (bf16)
  __shared__ unsigned short Vt[64 * 136];   // V^T
  const int w = blockIdx.x, H = blockIdx.y;
  const int tid = threadIdx.x, wave = tid >> 6, lane = tid & 63;
  const int q = lane >> 4, l = lane & 15;
  const size_t slab = (size_t)(w * 8 + H) * 8192;  // 128x64
  const unsigned short* Qs = C + slab;
  const unsigned short* Ks = C + 16777216 + slab;
  const unsigned short* Vs = C + 33554432 + slab;
  // stage V^T: Vt[d][j] = V[j][d]
  for (int u = tid; u < 1024; u += 256) {
    const int j = u >> 3, db = u & 7;
    s16x8 v = *(const s16x8*)(Vs + j * 64 + db * 8);
#pragma unroll
    for (int t = 0; t < 8; ++t) Vt[(db * 8 + t) * 136 + j] = v[t];
  }
  // S = q k^T * scale; wave handles 32 rows
  const int m0 = wave * 32;
  f32x4 acc[2][8] = {};
#pragma unroll
  for (int ks = 0; ks < 2; ++ks) {
    const int kk = ks * 32 + q * 8;
    s16x8 a[2], b[8];
#pragma unroll
    for (int i = 0; i < 2; ++i) a[i] = *(const s16x8*)(Qs + (m0 + i * 16 + l) * 64 + kk);
#pragma unroll
    for (int j = 0; j < 8; ++j) b[j] = *(const s16x8*)(Ks + (j * 16 + l) * 64 + kk);
#pragma unroll
    for (int i = 0; i < 2; ++i)
#pragma unroll
      for (int j = 0; j < 8; ++j) acc[i][j] = MFMA16(a[i], b[j], acc[i][j]);
  }
  // in-register softmax per owned row; write normalized bf16 P to LDS
#pragma unroll
  for (int i = 0; i < 2; ++i)
#pragma unroll
    for (int r = 0; r < 4; ++r) {
      float v[8];
#pragma unroll
      for (int j = 0; j < 8; ++j) v[j] = acc[i][j][r] * 0.125f;
      float mx = fmaxf(fmaxf(fmaxf(v[0], v[1]), fmaxf(v[2], v[3])),
                       fmaxf(fmaxf(v[4], v[5]), fmaxf(v[6], v[7])));
      mx = fmaxf(mx, __shfl_xor(mx, 1));
      mx = fmaxf(mx, __shfl_xor(mx, 2));
      mx = fmaxf(mx, __shfl_xor(mx, 4));
      mx = fmaxf(mx, __shfl_xor(mx, 8));
      float s = 0.f;
#pragma unroll
      for (int j = 0; j < 8; ++j) { v[j] = __expf(v[j] - mx); s += v[j]; }
      s += __shfl_xor(s, 1);
      s += __shfl_xor(s, 2);
      s += __shfl_xor(s, 4);
      s += __shfl_xor(s, 8);
      const float inv = 1.0f / s;
      const int row = m0 + i * 16 + q * 4 + r;
#pragma unroll
      for (int j = 0; j < 8; ++j) Sp[row * 136 + j * 16 + l] = f2b(v[j] * inv);
    }
  __syncthreads();  // covers V^T staging and P visibility
  // O = P @ V
  f32x4 o[2][4] = {};
#pragma unroll
  for (int ks = 0; ks < 4; ++ks) {
    const int kk = ks * 32 + q * 8;
    s16x8 a[2], b[4];
#pragma unroll
    for (int i = 0; i < 2; ++i) a[i] = *(const s16x8*)(&Sp[(m0 + i * 16 + l) * 136 + kk]);
#pragma unroll
    for (int j = 0; j < 4; ++j) b[j] = *(const s16x8*)(&Vt[(j * 16 + l) * 136 + kk]);
#pragma unroll
    for (int i = 0; i < 2; ++i)
#pragma unroll
      for (int j = 0; j < 4; ++j) o[i][j] = MFMA16(a[i], b[j], o[i][j]);
  }
#pragma unroll
  for (int i = 0; i < 2; ++i)
#pragma unroll
    for (int j = 0; j < 4; ++j)
#pragma unroll
      for (int r = 0; r < 4; ++r) {
        const int row = m0 + i * 16 + q * 4 + r;  // seq pos (h index)
        const int d = j * 16 + l;
        O[(size_t)(row * 256 + w) * 1024 + H * 64 + d] = f2b(o[i][j][r]);
      }
}

// ---------------- tied row attention dots, split-K over 8 chunks of 16 rows ----------------
__global__ __launch_bounds__(256) void row_dots(const unsigned short* __restrict__ C,
                                                float* __restrict__ dp) {
  const int H = blockIdx.z;
  const int r0 = blockIdx.y * 16;
  const int ti = blockIdx.x & 1, tj = blockIdx.x >> 1;
  const int tid = threadIdx.x, wave = tid >> 6, lane = tid & 63;
  const int q = lane >> 4, l = lane & 15;
  const int m0 = ti * 128 + (wave >> 1) * 64;
  const int n0 = tj * 128 + (wave & 1) * 64;
  const unsigned short* Qh = C;
  const unsigned short* Kh = C + 16777216;
  f32x4 acc[4][4] = {};
  for (int ks = 0; ks < 32; ++ks) {
    const int k = ks * 32 + q * 8;
    const int rr = r0 + (k >> 6), d = k & 63;
    const size_t slab = (size_t)(rr * 8 + H) * 16384;  // 256x64
    s16x8 a[4], b[4];
#pragma unroll
    for (int i = 0; i < 4; ++i) a[i] = *(const s16x8*)(Qh + slab + (m0 + i * 16 + l) * 64 + d);
#pragma unroll
    for (int j = 0; j < 4; ++j) b[j] = *(const s16x8*)(Kh + slab + (n0 + j * 16 + l) * 64 + d);
#pragma unroll
    for (int i = 0; i < 4; ++i)
#pragma unroll
      for (int j = 0; j < 4; ++j) acc[i][j] = MFMA16(a[i], b[j], acc[i][j]);
  }
  float* outp = dp + ((size_t)blockIdx.y * 8 + H) * 65536;
#pragma unroll
  for (int i = 0; i < 4; ++i)
#pragma unroll
    for (int j = 0; j < 4; ++j)
#pragma unroll
      for (int r = 0; r < 4; ++r)
        outp[(size_t)(m0 + i * 16 + q * 4 + r) * 256 + n0 + j * 16 + l] = acc[i][j][r];
}

__global__ __launch_bounds__(256) void row_softmax(const float* __restrict__ dp,
                                                   unsigned short* __restrict__ attn) {
  const int row = blockIdx.x;  // H*256 + i
  const int H = row >> 8, i = row & 255;
  const int t = threadIdx.x, wave = t >> 6, lane = t & 63;
  __shared__ float red[8];
  float v = 0.f;
#pragma unroll
  for (int c = 0; c < 8; ++c) v += dp[((size_t)c * 8 + H) * 65536 + (size_t)i * 256 + t];
  v *= 1.1048543456e-2f;  // 0.125 / sqrt(128)
  float m = v;
  for (int o = 32; o > 0; o >>= 1) m = fmaxf(m, __shfl_xor(m, o, 64));
  if (lane == 0) red[wave] = m;
  __syncthreads();
  const float M = fmaxf(fmaxf(red[0], red[1]), fmaxf(red[2], red[3]));
  const float e = __expf(v - M);
  float s = e;
  for (int o = 32; o > 0; o >>= 1) s += __shfl_xor(s, o, 64);
  if (lane == 0) red[4 + wave] = s;
  __syncthreads();
  const float S = red[4] + red[5] + red[6] + red[7];
  attn[(size_t)row * 256 + t] = f2b(e / S);
}

// ---------------- row attention PV: one block per (r, H) ----------------
__global__ __launch_bounds__(256) void row_pv(const unsigned short* __restrict__ C,
                                              const unsigned short* __restrict__ attn,
                                              unsigned short* __restrict__ O) {
  __shared__ unsigned short Vt[64 * 264];
  const int r = blockIdx.x, H = blockIdx.y;
  const int tid = threadIdx.x, wave = tid >> 6, lane = tid & 63;
  const int q = lane >> 4, l = lane & 15;
  const unsigned short* Vs = C + 33554432 + (size_t)(r * 8 + H) * 16384;
  for (int u = tid; u < 2048; u += 256) {
    const int j = u >> 3, db = u & 7;
    s16x8 v = *(const s16x8*)(Vs + j * 64 + db * 8);
#pragma unroll
    for (int t = 0; t < 8; ++t) Vt[(db * 8 + t) * 264 + j] = v[t];
  }
  __syncthreads();
  const unsigned short* A = attn + (size_t)H * 65536;
  const int m0 = wave * 64;
  f32x4 acc[4][4] = {};
#pragma unroll
  for (int ks = 0; ks < 8; ++ks) {
    const int kk = ks * 32 + q * 8;
    s16x8 a[4], b[4];
#pragma unroll
    for (int i = 0; i < 4; ++i) a[i] = *(const s16x8*)(A + (size_t)(m0 + i * 16 + l) * 256 + kk);
#pragma unroll
    for (int j = 0; j < 4; ++j) b[j] = *(const s16x8*)(&Vt[(j * 16 + l) * 264 + kk]);
#pragma unroll
    for (int i = 0; i < 4; ++i)
#pragma unroll
      for (int j = 0; j < 4; ++j) acc[i][j] = MFMA16(a[i], b[j], acc[i][j]);
  }
#pragma unroll
  for (int i = 0; i < 4; ++i)
#pragma unroll
    for (int j = 0; j < 4; ++j)
#pragma unroll
      for (int rr = 0; rr < 4; ++rr) {
        const int iw = m0 + i * 16 + q * 4 + rr;  // w index
        const int d = j * 16 + l;
        O[(size_t)(r * 256 + iw) * 1024 + 512 + H * 64 + d] = f2b(acc[i][j][rr]);
      }
}

// ---------------- output projection, direct global->VGPR (no LDS, no barriers) ----------------
// Block = 64 m-rows x 256 n-cols (full N); 4 waves, each 64x64.
// W2T (0.5 MB) is L2-resident; Ocat rows read exactly once chip-wide.
// MFMA operands SWAPPED: lane holds 4 consecutive cols for fixed row -> float4 stores.
__global__ __launch_bounds__(256) void out_proj(const unsigned short* __restrict__ O,
                                                const unsigned short* __restrict__ W2T,
                                                const float* __restrict__ bw,
                                                const float* __restrict__ bh,
                                                float* __restrict__ out) {
  const int tid = threadIdx.x, wave = tid >> 6, lane = tid & 63;
  const int q = lane >> 4, l = lane & 15;
  const int m0 = blockIdx.x * 64;
  const int nw = wave * 64;
  f32x4 acc[4][4] = {};
#pragma unroll
  for (int ks = 0; ks < 32; ++ks) {
    const int kk = ks * 32 + q * 8;
    s16x8 a[4], b[4];
#pragma unroll
    for (int i = 0; i < 4; ++i)
      a[i] = *(const s16x8*)(O + (size_t)(m0 + i * 16 + l) * 1024 + kk);
#pragma unroll
    for (int j = 0; j < 4; ++j)
      b[j] = *(const s16x8*)(W2T + (size_t)(nw + j * 16 + l) * 1024 + kk);
#pragma unroll
    for (int i = 0; i < 4; ++i)
#pragma unroll
      for (int j = 0; j < 4; ++j) acc[i][j] = MFMA16(b[j], a[i], acc[i][j]);  // swapped: D^T
  }
#pragma unroll
  for (int i = 0; i < 4; ++i) {
    const int m = m0 + i * 16 + l;
#pragma unroll
    for (int j = 0; j < 4; ++j) {
      const int col = nw + j * 16 + q * 4;
      const float4 bwv = *(const float4*)(bw + col);
      const float4 bhv = *(const float4*)(bh + col);
      float4 ov;
      ov.x = acc[i][j][0] + bwv.x + bhv.x;
      ov.y = acc[i][j][1] + bwv.y + bhv.y;
      ov.z = acc[i][j][2] + bwv.z + bhv.z;
      ov.w = acc[i][j][3] + bwv.w + bhv.w;
      *(float4*)(out + (size_t)m * 256 + col) = ov;
    }
  }
}

extern "C" void kernel_launch(void* const* d_in, const int* in_sizes, int n_in,
                              void* d_out, int out_size, void* d_ws, size_t ws_size,
                              hipStream_t stream) {
  const float* x    = (const float*)d_in[0];
  const float* wq   = (const float*)d_in[1];
  const float* wkv  = (const float*)d_in[2];
  const float* wout = (const float*)d_in[3];
  const float* bw   = (const float*)d_in[4];
  const float* hq   = (const float*)d_in[5];
  const float* hkv  = (const float*)d_in[6];
  const float* hout = (const float*)d_in[7];
  const float* bh   = (const float*)d_in[8];
  float* out = (float*)d_out;

  char* ws = (char*)d_ws;
  unsigned short* x_bf  = (unsigned short*)(ws);               // 16 MB
  unsigned short* WcatT = (unsigned short*)(ws + 16777216);    // 1.5 MB
  unsigned short* W2T   = (unsigned short*)(ws + 18350080);    // 0.5 MB
  float*          dp    = (float*)(ws + 18874368);             // 16 MB
  unsigned short* attn  = (unsigned short*)(ws + 35651584);    // 1 MB
  unsigned short* Ocat  = (unsigned short*)(ws + 36700160);    // 64 MB
  unsigned short* Cproj = (unsigned short*)(ws + 103809024);   // 96 MB (reused per branch)

  cvt_x<<<8192, 256, 0, stream>>>(x, x_bf);
  build_wt<<<3072, 256, 0, stream>>>(wq, wkv, hq, hkv, WcatT);
  build_w2t<<<256, 256, 0, stream>>>(wout, hout, W2T);

  // w-branch (column attention)
  gemm_qkv<<<dim3(512, 6), 256, 0, stream>>>(x_bf, WcatT, Cproj, 0);
  col_attn<<<dim3(256, 8), 256, 0, stream>>>(Cproj, Ocat);
  // h-branch (tied row attention), reuses Cproj
  gemm_qkv<<<dim3(512, 6), 256, 0, stream>>>(x_bf, WcatT + 1536 * 256, Cproj, 1);
  row_dots<<<dim3(4, 8, 8), 256, 0, stream>>>(Cproj, dp);
  row_softmax<<<2048, 256, 0, stream>>>(dp, attn);
  row_pv<<<dim3(128, 8), 256, 0, stream>>>(Cproj, attn, Ocat);
  out_proj<<<512, 256, 0, stream>>>(Ocat, W2T, bw, bh, out);
}

// Round 7
// 466.928 us; speedup vs baseline: 1.0625x; 1.0625x over previous
//
#include <hip/hip_runtime.h>

typedef short s16x8 __attribute__((ext_vector_type(8)));
typedef float f32x4 __attribute__((ext_vector_type(4)));

#define MFMA16(a, b, c) __builtin_amdgcn_mfma_f32_16x16x32_bf16((a), (b), (c), 0, 0, 0)

__device__ __forceinline__ unsigned short f2b(float f) {
  union { float f; unsigned int u; } v; v.f = f;
  unsigned int u = v.u;
  unsigned int r = (u + 0x7fffu + ((u >> 16) & 1u)) >> 16;  // RNE
  return (unsigned short)r;
}
__device__ __forceinline__ float b2f(unsigned short b) {
  union { unsigned int u; float f; } v; v.u = ((unsigned int)b) << 16;
  return v.f;
}

__device__ __forceinline__ void gld_lds16(const void* g, void* l) {
  __builtin_amdgcn_global_load_lds(
      (const __attribute__((address_space(1))) unsigned int*)g,
      (__attribute__((address_space(3))) unsigned int*)l, 16, 0, 0);
}

// ---------------- prep ----------------
__global__ __launch_bounds__(256) void cvt_x(const float* __restrict__ x,
                                             unsigned short* __restrict__ xb) {
  size_t i = ((size_t)blockIdx.x * 256 + threadIdx.x) * 4;
  float4 v = *(const float4*)(x + i);
  ushort4 o;
  o.x = f2b(v.x); o.y = f2b(v.y); o.z = f2b(v.z); o.w = f2b(v.w);
  *(ushort4*)(xb + i) = o;
}

// WcatT[n][k] = W[k][n], n in [0,3072): [wq | wkv | hq | hkv]
__global__ __launch_bounds__(256) void build_wt(const float* __restrict__ wq,
                                                const float* __restrict__ wkv,
                                                const float* __restrict__ hq,
                                                const float* __restrict__ hkv,
                                                unsigned short* __restrict__ WT) {
  const int n = blockIdx.x, k = threadIdx.x;
  float v;
  if (n < 512)       v = wq [(size_t)k * 512  + n];
  else if (n < 1536) v = wkv[(size_t)k * 1024 + (n - 512)];
  else if (n < 2048) v = hq [(size_t)k * 512  + (n - 1536)];
  else               v = hkv[(size_t)k * 1024 + (n - 2048)];
  WT[(size_t)n * 256 + k] = f2b(v);
}

// W2T[n][k] = [wout;hout][k][n], n<256, k<1024
__global__ __launch_bounds__(256) void build_w2t(const float* __restrict__ wout,
                                                 const float* __restrict__ hout,
                                                 unsigned short* __restrict__ W2T) {
  const int n = blockIdx.x;
  for (int k = threadIdx.x; k < 1024; k += 256) {
    const float v = (k < 512) ? wout[(size_t)k * 256 + n] : hout[(size_t)(k - 512) * 256 + n];
    W2T[(size_t)n * 1024 + k] = f2b(v);
  }
}

// ---------------- fused col branch: projection + attention, one block per w ----------------
// Stage X column (128 h-rows x 256 k) once in LDS (XOR-swizzled), then per H:
//   QKV = Xw @ W_H (B-frags straight from L2-resident WcatT; no barriers in K-loop)
//   -> Q,K (D^T order, [128][72] padded) and V^T (normal order, [64][136]) in LDS
//   -> QK^T + in-register softmax -> P in LDS -> PV -> O.
__global__ __launch_bounds__(512) void fused_col(const unsigned short* __restrict__ X,
                                                 const unsigned short* __restrict__ WT,
                                                 unsigned short* __restrict__ O) {
  __shared__ __align__(16) char lds[154624];
  unsigned short* Sp = (unsigned short*)(lds + 119808);  // [128][136]
  const int w = blockIdx.x;
  const int tid = threadIdx.x, wave = tid >> 6, lane = tid & 63;
  const int q = lane >> 4, l = lane & 15;
  const int mt = wave * 16;
  const char* Xl = lds;            // [128] rows x 512 B, 16B-chunk swizzled: c ^= row&7
  char* Ql = lds + 65536;          // [128] x 144 B
  char* Kl = lds + 83968;          // [128] x 144 B
  char* Vt = lds + 102400;         // [64]  x 272 B (V^T)
  // stage X column w: linear LDS chunk u=(row,c) <- global chunk (row, c^(row&7))
  {
    const char* Xb = (const char*)X;
#pragma unroll
    for (int it = 0; it < 8; ++it) {
      const int u = it * 512 + wave * 64 + lane;
      const int row = u >> 5, c = u & 31;
      gld_lds16(Xb + ((size_t)(row * 256 + w)) * 512 + ((c ^ (row & 7)) * 16),
                (char*)lds + (it * 512 + wave * 64) * 16);
    }
  }
  __syncthreads();
  for (int H = 0; H < 8; ++H) {
    // ---- projections (wave owns rows mt..mt+15)
    f32x4 accq[4] = {}, acck[4] = {}, accv[4] = {};
#pragma unroll
    for (int ks = 0; ks < 8; ++ks) {
      const int kk = ks * 32 + q * 8;
      const int c = kk >> 3;
      const int row = mt + l;
      s16x8 a = *(const s16x8*)(Xl + (size_t)row * 512 + ((c ^ (row & 7)) * 16));
      s16x8 bq[4], bk[4], bv[4];
#pragma unroll
      for (int j = 0; j < 4; ++j) {
        bq[j] = *(const s16x8*)(WT + (size_t)(H * 64 + j * 16 + l) * 256 + kk);
        bk[j] = *(const s16x8*)(WT + (size_t)(512 + H * 64 + j * 16 + l) * 256 + kk);
        bv[j] = *(const s16x8*)(WT + (size_t)(1024 + H * 64 + j * 16 + l) * 256 + kk);
      }
#pragma unroll
      for (int j = 0; j < 4; ++j) {
        accq[j] = MFMA16(bq[j], a, accq[j]);  // D^T: lane -> Q[mt+l][j*16+q*4+r]
        acck[j] = MFMA16(bk[j], a, acck[j]);
        accv[j] = MFMA16(a, bv[j], accv[j]);  // normal: lane -> V[mt+q*4+r][j*16+l]
      }
    }
#pragma unroll
    for (int j = 0; j < 4; ++j) {
      ushort4 oq, ok, ov;
      oq.x = f2b(accq[j][0]); oq.y = f2b(accq[j][1]); oq.z = f2b(accq[j][2]); oq.w = f2b(accq[j][3]);
      ok.x = f2b(acck[j][0]); ok.y = f2b(acck[j][1]); ok.z = f2b(acck[j][2]); ok.w = f2b(acck[j][3]);
      ov.x = f2b(accv[j][0]); ov.y = f2b(accv[j][1]); ov.z = f2b(accv[j][2]); ov.w = f2b(accv[j][3]);
      *(ushort4*)(Ql + (size_t)(mt + l) * 144 + (j * 16 + q * 4) * 2) = oq;
      *(ushort4*)(Kl + (size_t)(mt + l) * 144 + (j * 16 + q * 4) * 2) = ok;
      *(ushort4*)(Vt + (size_t)(j * 16 + l) * 272 + (mt + q * 4) * 2) = ov;
    }
    __syncthreads();
    // ---- S = Q K^T * 0.125; in-register softmax; normalized P -> Sp
    {
      f32x4 s[8] = {};
#pragma unroll
      for (int ks = 0; ks < 2; ++ks) {
        const int kb = ks * 64 + q * 16;  // byte offset within 144-B row
        s16x8 aq = *(const s16x8*)(Ql + (size_t)(mt + l) * 144 + kb);
        s16x8 bk[8];
#pragma unroll
        for (int j = 0; j < 8; ++j)
          bk[j] = *(const s16x8*)(Kl + (size_t)(j * 16 + l) * 144 + kb);
#pragma unroll
        for (int j = 0; j < 8; ++j) s[j] = MFMA16(aq, bk[j], s[j]);
      }
#pragma unroll
      for (int r = 0; r < 4; ++r) {
        float v[8];
#pragma unroll
        for (int j = 0; j < 8; ++j) v[j] = s[j][r] * 0.125f;
        float mx = fmaxf(fmaxf(fmaxf(v[0], v[1]), fmaxf(v[2], v[3])),
                         fmaxf(fmaxf(v[4], v[5]), fmaxf(v[6], v[7])));
        mx = fmaxf(mx, __shfl_xor(mx, 1));
        mx = fmaxf(mx, __shfl_xor(mx, 2));
        mx = fmaxf(mx, __shfl_xor(mx, 4));
        mx = fmaxf(mx, __shfl_xor(mx, 8));
        float sm = 0.f;
#pragma unroll
        for (int j = 0; j < 8; ++j) { v[j] = __expf(v[j] - mx); sm += v[j]; }
        sm += __shfl_xor(sm, 1);
        sm += __shfl_xor(sm, 2);
        sm += __shfl_xor(sm, 4);
        sm += __shfl_xor(sm, 8);
        const float inv = 1.0f / sm;
        const int row = mt + q * 4 + r;
#pragma unroll
        for (int j = 0; j < 8; ++j) Sp[row * 136 + j * 16 + l] = f2b(v[j] * inv);
      }
    }
    __syncthreads();
    // ---- O = P @ V  (Sp rows are wave-private; Vt needs the barrier above)
    {
      f32x4 o[4] = {};
#pragma unroll
      for (int ks = 0; ks < 4; ++ks) {
        const int kb = ks * 64 + q * 16;  // byte offset within 272-B row
        s16x8 ap = *(const s16x8*)((const char*)Sp + (size_t)(mt + l) * 272 + kb);
        s16x8 bv[4];
#pragma unroll
        for (int j = 0; j < 4; ++j)
          bv[j] = *(const s16x8*)(Vt + (size_t)(j * 16 + l) * 272 + kb);
#pragma unroll
        for (int j = 0; j < 4; ++j) o[j] = MFMA16(ap, bv[j], o[j]);
      }
#pragma unroll
      for (int j = 0; j < 4; ++j)
#pragma unroll
        for (int r = 0; r < 4; ++r) {
          const int row = mt + q * 4 + r;  // h index
          O[(size_t)(row * 256 + w) * 1024 + H * 64 + j * 16 + l] = f2b(o[j][r]);
        }
    }
    __syncthreads();  // Vt/Sp reuse next H
  }
}

// ---------------- QKV projection (row branch), LDS-staged 128x128 ----------------
// C layout (per part q/k/v of 16777216 elems): part + ((r*8+H)*256 + i)*64 + d
// MFMA operands SWAPPED: lane holds 4 consecutive n for fixed m -> ushort4 stores.
__global__ __launch_bounds__(256) void gemm_qkv(const unsigned short* __restrict__ X,
                                                const unsigned short* __restrict__ WT,
                                                unsigned short* __restrict__ C,
                                                int branch) {
  __shared__ unsigned short As[128 * 32];
  __shared__ unsigned short Bs[128 * 32];
  const int tid = threadIdx.x, wave = tid >> 6, lane = tid & 63;
  const int q = lane >> 4, l = lane & 15;
  const int m0 = blockIdx.x * 128;
  const int n0 = blockIdx.y * 128;
  const int mt = (wave >> 1) * 64;  // wave tile row in block
  const int nt = (wave & 1) * 64;
  const char* Xb = (const char*)X;
  const char* Wb = (const char*)WT;
  const int srow = wave * 32 + (lane >> 2);  // staging row (+16 for second half)
  const int sboff = (lane & 3) * 16;         // byte offset within 64-B row chunk
  char* AsB = (char*)As;
  char* BsB = (char*)Bs;
  f32x4 acc[4][4] = {};
#pragma unroll
  for (int ks = 0; ks < 8; ++ks) {
    const int kb = ks * 64;  // byte offset of k-chunk within 512-B row
    gld_lds16(Xb + (size_t)(m0 + srow) * 512 + kb + sboff, AsB + wave * 2048);
    gld_lds16(Xb + (size_t)(m0 + srow + 16) * 512 + kb + sboff, AsB + wave * 2048 + 1024);
    gld_lds16(Wb + (size_t)(n0 + srow) * 512 + kb + sboff, BsB + wave * 2048);
    gld_lds16(Wb + (size_t)(n0 + srow + 16) * 512 + kb + sboff, BsB + wave * 2048 + 1024);
    __syncthreads();
    s16x8 a[4], b[4];
#pragma unroll
    for (int i = 0; i < 4; ++i) a[i] = *(const s16x8*)(&As[(mt + i * 16 + l) * 32 + q * 8]);
#pragma unroll
    for (int j = 0; j < 4; ++j) b[j] = *(const s16x8*)(&Bs[(nt + j * 16 + l) * 32 + q * 8]);
#pragma unroll
    for (int i = 0; i < 4; ++i)
#pragma unroll
      for (int j = 0; j < 4; ++j) acc[i][j] = MFMA16(b[j], a[i], acc[i][j]);  // swapped: D^T
    __syncthreads();
  }
  // epilogue: lane (q,l) frag (i,j) holds m = m0+mt+i*16+l, n = n0+nt+j*16+q*4 .. +3
#pragma unroll
  for (int i = 0; i < 4; ++i) {
    const int m = m0 + mt + i * 16 + l;
    const int mrow = (branch == 0) ? ((m & 255) * 8) : ((m >> 8) * 8);
    const int mcol = (branch == 0) ? (m >> 8) : (m & 255);
    const int mdim = (branch == 0) ? 128 : 256;
#pragma unroll
    for (int j = 0; j < 4; ++j) {
      const int n = n0 + nt + j * 16 + q * 4;
      const int part = n >> 9, H = (n & 511) >> 6, d = n & 63;
      ushort4 o;
      o.x = f2b(acc[i][j][0]); o.y = f2b(acc[i][j][1]);
      o.z = f2b(acc[i][j][2]); o.w = f2b(acc[i][j][3]);
      unsigned short* base = C + (size_t)part * 16777216;
      const size_t idx = ((size_t)(mrow + H) * mdim + mcol) * 64 + d;
      *(ushort4*)(base + idx) = o;
    }
  }
}

// ---------------- tied row attention dots, split-K over 8 chunks of 16 rows ----------------
__global__ __launch_bounds__(256) void row_dots(const unsigned short* __restrict__ C,
                                                float* __restrict__ dp) {
  const int H = blockIdx.z;
  const int r0 = blockIdx.y * 16;
  const int ti = blockIdx.x & 1, tj = blockIdx.x >> 1;
  const int tid = threadIdx.x, wave = tid >> 6, lane = tid & 63;
  const int q = lane >> 4, l = lane & 15;
  const int m0 = ti * 128 + (wave >> 1) * 64;
  const int n0 = tj * 128 + (wave & 1) * 64;
  const unsigned short* Qh = C;
  const unsigned short* Kh = C + 16777216;
  f32x4 acc[4][4] = {};
  for (int ks = 0; ks < 32; ++ks) {
    const int k = ks * 32 + q * 8;
    const int rr = r0 + (k >> 6), d = k & 63;
    const size_t slab = (size_t)(rr * 8 + H) * 16384;  // 256x64
    s16x8 a[4], b[4];
#pragma unroll
    for (int i = 0; i < 4; ++i) a[i] = *(const s16x8*)(Qh + slab + (m0 + i * 16 + l) * 64 + d);
#pragma unroll
    for (int j = 0; j < 4; ++j) b[j] = *(const s16x8*)(Kh + slab + (n0 + j * 16 + l) * 64 + d);
#pragma unroll
    for (int i = 0; i < 4; ++i)
#pragma unroll
      for (int j = 0; j < 4; ++j) acc[i][j] = MFMA16(a[i], b[j], acc[i][j]);
  }
  float* outp = dp + ((size_t)blockIdx.y * 8 + H) * 65536;
#pragma unroll
  for (int i = 0; i < 4; ++i)
#pragma unroll
    for (int j = 0; j < 4; ++j)
#pragma unroll
      for (int r = 0; r < 4; ++r)
        outp[(size_t)(m0 + i * 16 + q * 4 + r) * 256 + n0 + j * 16 + l] = acc[i][j][r];
}

__global__ __launch_bounds__(256) void row_softmax(const float* __restrict__ dp,
                                                   unsigned short* __restrict__ attn) {
  const int row = blockIdx.x;  // H*256 + i
  const int H = row >> 8, i = row & 255;
  const int t = threadIdx.x, wave = t >> 6, lane = t & 63;
  __shared__ float red[8];
  float v = 0.f;
#pragma unroll
  for (int c = 0; c < 8; ++c) v += dp[((size_t)c * 8 + H) * 65536 + (size_t)i * 256 + t];
  v *= 1.1048543456e-2f;  // 0.125 / sqrt(128)
  float m = v;
  for (int o = 32; o > 0; o >>= 1) m = fmaxf(m, __shfl_xor(m, o, 64));
  if (lane == 0) red[wave] = m;
  __syncthreads();
  const float M = fmaxf(fmaxf(red[0], red[1]), fmaxf(red[2], red[3]));
  const float e = __expf(v - M);
  float s = e;
  for (int o = 32; o > 0; o >>= 1) s += __shfl_xor(s, o, 64);
  if (lane == 0) red[4 + wave] = s;
  __syncthreads();
  const float S = red[4] + red[5] + red[6] + red[7];
  attn[(size_t)row * 256 + t] = f2b(e / S);
}

// ---------------- row attention PV: one block per (r, H) ----------------
__global__ __launch_bounds__(256) void row_pv(const unsigned short* __restrict__ C,
                                              const unsigned short* __restrict__ attn,
                                              unsigned short* __restrict__ O) {
  __shared__ unsigned short Vt[64 * 264];
  const int r = blockIdx.x, H = blockIdx.y;
  const int tid = threadIdx.x, wave = tid >> 6, lane = tid & 63;
  const int q = lane >> 4, l = lane & 15;
  const unsigned short* Vs = C + 33554432 + (size_t)(r * 8 + H) * 16384;
  for (int u = tid; u < 2048; u += 256) {
    const int j = u >> 3, db = u & 7;
    s16x8 v = *(const s16x8*)(Vs + j * 64 + db * 8);
#pragma unroll
    for (int t = 0; t < 8; ++t) Vt[(db * 8 + t) * 264 + j] = v[t];
  }
  __syncthreads();
  const unsigned short* A = attn + (size_t)H * 65536;
  const int m0 = wave * 64;
  f32x4 acc[4][4] = {};
#pragma unroll
  for (int ks = 0; ks < 8; ++ks) {
    const int kk = ks * 32 + q * 8;
    s16x8 a[4], b[4];
#pragma unroll
    for (int i = 0; i < 4; ++i) a[i] = *(const s16x8*)(A + (size_t)(m0 + i * 16 + l) * 256 + kk);
#pragma unroll
    for (int j = 0; j < 4; ++j) b[j] = *(const s16x8*)(&Vt[(j * 16 + l) * 264 + kk]);
#pragma unroll
    for (int i = 0; i < 4; ++i)
#pragma unroll
      for (int j = 0; j < 4; ++j) acc[i][j] = MFMA16(a[i], b[j], acc[i][j]);
  }
#pragma unroll
  for (int i = 0; i < 4; ++i)
#pragma unroll
    for (int j = 0; j < 4; ++j)
#pragma unroll
      for (int rr = 0; rr < 4; ++rr) {
        const int iw = m0 + i * 16 + q * 4 + rr;  // w index
        const int d = j * 16 + l;
        O[(size_t)(r * 256 + iw) * 1024 + 512 + H * 64 + d] = f2b(acc[i][j][rr]);
      }
}

// ---------------- output projection with LDS staging: out = Ocat(32768x1024) @ W2 + bias ----------------
// MFMA operands SWAPPED: lane holds 4 consecutive cols for fixed row -> float4 stores.
__global__ __launch_bounds__(256) void out_proj(const unsigned short* __restrict__ O,
                                                const unsigned short* __restrict__ W2T,
                                                const float* __restrict__ bw,
                                                const float* __restrict__ bh,
                                                float* __restrict__ out) {
  __shared__ unsigned short As[128 * 32];
  __shared__ unsigned short Bs[128 * 32];
  const int tid = threadIdx.x, wave = tid >> 6, lane = tid & 63;
  const int q = lane >> 4, l = lane & 15;
  const int m0 = blockIdx.x * 128;
  const int n0 = blockIdx.y * 128;
  const int mt = (wave >> 1) * 64;
  const int nt = (wave & 1) * 64;
  const char* Ob = (const char*)O;
  const char* Wb = (const char*)W2T;
  const int srow = wave * 32 + (lane >> 2);
  const int sboff = (lane & 3) * 16;
  char* AsB = (char*)As;
  char* BsB = (char*)Bs;
  f32x4 acc[4][4] = {};
  for (int ks = 0; ks < 32; ++ks) {
    const int kb = ks * 64;  // byte offset within 2048-B row
    gld_lds16(Ob + (size_t)(m0 + srow) * 2048 + kb + sboff, AsB + wave * 2048);
    gld_lds16(Ob + (size_t)(m0 + srow + 16) * 2048 + kb + sboff, AsB + wave * 2048 + 1024);
    gld_lds16(Wb + (size_t)(n0 + srow) * 2048 + kb + sboff, BsB + wave * 2048);
    gld_lds16(Wb + (size_t)(n0 + srow + 16) * 2048 + kb + sboff, BsB + wave * 2048 + 1024);
    __syncthreads();
    s16x8 a[4], b[4];
#pragma unroll
    for (int i = 0; i < 4; ++i) a[i] = *(const s16x8*)(&As[(mt + i * 16 + l) * 32 + q * 8]);
#pragma unroll
    for (int j = 0; j < 4; ++j) b[j] = *(const s16x8*)(&Bs[(nt + j * 16 + l) * 32 + q * 8]);
#pragma unroll
    for (int i = 0; i < 4; ++i)
#pragma unroll
      for (int j = 0; j < 4; ++j) acc[i][j] = MFMA16(b[j], a[i], acc[i][j]);  // swapped: D^T
    __syncthreads();
  }
#pragma unroll
  for (int i = 0; i < 4; ++i) {
    const int m = m0 + mt + i * 16 + l;
#pragma unroll
    for (int j = 0; j < 4; ++j) {
      const int col = n0 + nt + j * 16 + q * 4;
      const float4 bwv = *(const float4*)(bw + col);
      const float4 bhv = *(const float4*)(bh + col);
      float4 ov;
      ov.x = acc[i][j][0] + bwv.x + bhv.x;
      ov.y = acc[i][j][1] + bwv.y + bhv.y;
      ov.z = acc[i][j][2] + bwv.z + bhv.z;
      ov.w = acc[i][j][3] + bwv.w + bhv.w;
      *(float4*)(out + (size_t)m * 256 + col) = ov;
    }
  }
}

extern "C" void kernel_launch(void* const* d_in, const int* in_sizes, int n_in,
                              void* d_out, int out_size, void* d_ws, size_t ws_size,
                              hipStream_t stream) {
  const float* x    = (const float*)d_in[0];
  const float* wq   = (const float*)d_in[1];
  const float* wkv  = (const float*)d_in[2];
  const float* wout = (const float*)d_in[3];
  const float* bw   = (const float*)d_in[4];
  const float* hq   = (const float*)d_in[5];
  const float* hkv  = (const float*)d_in[6];
  const float* hout = (const float*)d_in[7];
  const float* bh   = (const float*)d_in[8];
  float* out = (float*)d_out;

  char* ws = (char*)d_ws;
  unsigned short* x_bf  = (unsigned short*)(ws);               // 16 MB
  unsigned short* WcatT = (unsigned short*)(ws + 16777216);    // 1.5 MB
  unsigned short* W2T   = (unsigned short*)(ws + 18350080);    // 0.5 MB
  float*          dp    = (float*)(ws + 18874368);             // 16 MB
  unsigned short* attn  = (unsigned short*)(ws + 35651584);    // 1 MB
  unsigned short* Ocat  = (unsigned short*)(ws + 36700160);    // 64 MB
  unsigned short* Cproj = (unsigned short*)(ws + 103809024);   // 96 MB (row branch)

  cvt_x<<<8192, 256, 0, stream>>>(x, x_bf);
  build_wt<<<3072, 256, 0, stream>>>(wq, wkv, hq, hkv, WcatT);
  build_w2t<<<256, 256, 0, stream>>>(wout, hout, W2T);

  // w-branch (column attention): fused projection + attention
  fused_col<<<256, 512, 0, stream>>>(x_bf, WcatT, Ocat);
  // h-branch (tied row attention)
  gemm_qkv<<<dim3(256, 12), 256, 0, stream>>>(x_bf, WcatT + 1536 * 256, Cproj, 1);
  row_dots<<<dim3(4, 8, 8), 256, 0, stream>>>(Cproj, dp);
  row_softmax<<<2048, 256, 0, stream>>>(dp, attn);
  row_pv<<<dim3(128, 8), 256, 0, stream>>>(Cproj, attn, Ocat);
  out_proj<<<dim3(256, 2), 256, 0, stream>>>(Ocat, W2T, bw, bh, out);
}

// Round 9
// 388.804 us; speedup vs baseline: 1.2760x; 1.2009x over previous
//
#include <hip/hip_runtime.h>

typedef short s16x8 __attribute__((ext_vector_type(8)));
typedef float f32x4 __attribute__((ext_vector_type(4)));

#define MFMA16(a, b, c) __builtin_amdgcn_mfma_f32_16x16x32_bf16((a), (b), (c), 0, 0, 0)

__device__ __forceinline__ unsigned short f2b(float f) {
  union { float f; unsigned int u; } v; v.f = f;
  unsigned int u = v.u;
  unsigned int r = (u + 0x7fffu + ((u >> 16) & 1u)) >> 16;  // RNE
  return (unsigned short)r;
}
__device__ __forceinline__ float b2f(unsigned short b) {
  union { unsigned int u; float f; } v; v.u = ((unsigned int)b) << 16;
  return v.f;
}

__device__ __forceinline__ void gld_lds16(const void* g, void* l) {
  __builtin_amdgcn_global_load_lds(
      (const __attribute__((address_space(1))) unsigned int*)g,
      (__attribute__((address_space(3))) unsigned int*)l, 16, 0, 0);
}

// ---------------- prep ----------------
__global__ __launch_bounds__(256) void cvt_x(const float* __restrict__ x,
                                             unsigned short* __restrict__ xb) {
  size_t i = ((size_t)blockIdx.x * 256 + threadIdx.x) * 4;
  float4 v = *(const float4*)(x + i);
  ushort4 o;
  o.x = f2b(v.x); o.y = f2b(v.y); o.z = f2b(v.z); o.w = f2b(v.w);
  *(ushort4*)(xb + i) = o;
}

// WcatT[n][k] = W[k][n], n in [0,3072): [wq | wkv | hq | hkv]
__global__ __launch_bounds__(256) void build_wt(const float* __restrict__ wq,
                                                const float* __restrict__ wkv,
                                                const float* __restrict__ hq,
                                                const float* __restrict__ hkv,
                                                unsigned short* __restrict__ WT) {
  const int n = blockIdx.x, k = threadIdx.x;
  float v;
  if (n < 512)       v = wq [(size_t)k * 512  + n];
  else if (n < 1536) v = wkv[(size_t)k * 1024 + (n - 512)];
  else if (n < 2048) v = hq [(size_t)k * 512  + (n - 1536)];
  else               v = hkv[(size_t)k * 1024 + (n - 2048)];
  WT[(size_t)n * 256 + k] = f2b(v);
}

// W2T[n][k] = [wout;hout][k][n], n<256, k<1024
__global__ __launch_bounds__(256) void build_w2t(const float* __restrict__ wout,
                                                 const float* __restrict__ hout,
                                                 unsigned short* __restrict__ W2T) {
  const int n = blockIdx.x;
  for (int k = threadIdx.x; k < 1024; k += 256) {
    const float v = (k < 512) ? wout[(size_t)k * 256 + n] : hout[(size_t)(k - 512) * 256 + n];
    W2T[(size_t)n * 1024 + k] = f2b(v);
  }
}

// ---------------- QKV projection: full-panel LDS, ONE barrier ----------------
// K=256 is short: the whole A-panel (128x256 bf16 = 64 KB, contiguous) and
// B-panel (64 KB, contiguous) fit in LDS at once. Stage both with coalesced
// global_load_lds (XOR-swizzled source chunk: c ^= row&7, rule #21 pair with
// the read-side XOR), ONE __syncthreads, then all 128 MFMAs/wave barrier-free.
// MFMA operands SWAPPED: lane holds 4 consecutive n for fixed m -> ushort4 stores.
// C layout (per part q/k/v of 16777216 elems):
//   branch 0 (col attn): part + ((w*8+H)*128 + h)*64 + d     (slab = 128x64)
//   branch 1 (row attn): part + ((r*8+H)*256 + i)*64 + d     (slab = 256x64)
__global__ __launch_bounds__(256) void gemm_qkv(const unsigned short* __restrict__ X,
                                                const unsigned short* __restrict__ WT,
                                                unsigned short* __restrict__ C,
                                                int branch) {
  __shared__ __align__(16) unsigned short As[128 * 256];  // 64 KB
  __shared__ __align__(16) unsigned short Bs[128 * 256];  // 64 KB
  const int tid = threadIdx.x, wave = tid >> 6, lane = tid & 63;
  const int q = lane >> 4, l = lane & 15;
  const int n0 = blockIdx.x * 128;   // n fastest: 12 consecutive blocks share A panel
  const int m0 = blockIdx.y * 128;
  const int mt = (wave >> 1) * 64;
  const int nt = (wave & 1) * 64;
  const char* Xb = (const char*)X;
  const char* Wb = (const char*)WT;
  char* AsB = (char*)As;
  char* BsB = (char*)Bs;
  // stage both panels: linear LDS dest, XOR-swizzled global source chunk
#pragma unroll
  for (int it = 0; it < 16; ++it) {
    const int u = it * 256 + wave * 64 + lane;
    const int row = u >> 5, c = u & 31;               // 32 x 16B chunks per 512-B row
    const size_t goff = (size_t)row * 512 + ((c ^ (row & 7)) * 16);
    gld_lds16(Xb + (size_t)m0 * 512 + goff, AsB + it * 4096 + wave * 1024);
    gld_lds16(Wb + (size_t)n0 * 512 + goff, BsB + it * 4096 + wave * 1024);
  }
  __syncthreads();  // the ONLY barrier
  f32x4 acc[4][4] = {};
#pragma unroll
  for (int ks = 0; ks < 8; ++ks) {
    s16x8 a[4], b[4];
#pragma unroll
    for (int i = 0; i < 4; ++i) {
      const int row = mt + i * 16 + l;
      a[i] = *(const s16x8*)(AsB + (size_t)row * 512 + (((ks * 4 + q) ^ (row & 7)) * 16));
    }
#pragma unroll
    for (int j = 0; j < 4; ++j) {
      const int row = nt + j * 16 + l;
      b[j] = *(const s16x8*)(BsB + (size_t)row * 512 + (((ks * 4 + q) ^ (row & 7)) * 16));
    }
#pragma unroll
    for (int i = 0; i < 4; ++i)
#pragma unroll
      for (int j = 0; j < 4; ++j) acc[i][j] = MFMA16(b[j], a[i], acc[i][j]);  // swapped: D^T
  }
  // epilogue (identical to r4): lane (q,l) frag (i,j) holds m = m0+mt+i*16+l,
  // n = n0+nt+j*16+q*4 .. +3
#pragma unroll
  for (int i = 0; i < 4; ++i) {
    const int m = m0 + mt + i * 16 + l;
    const int mrow = (branch == 0) ? ((m & 255) * 8) : ((m >> 8) * 8);
    const int mcol = (branch == 0) ? (m >> 8) : (m & 255);
    const int mdim = (branch == 0) ? 128 : 256;
#pragma unroll
    for (int j = 0; j < 4; ++j) {
      const int n = n0 + nt + j * 16 + q * 4;
      const int part = n >> 9, H = (n & 511) >> 6, d = n & 63;
      ushort4 o;
      o.x = f2b(acc[i][j][0]); o.y = f2b(acc[i][j][1]);
      o.z = f2b(acc[i][j][2]); o.w = f2b(acc[i][j][3]);
      unsigned short* base = C + (size_t)part * 16777216;
      const size_t idx = ((size_t)(mrow + H) * mdim + mcol) * 64 + d;
      *(ushort4*)(base + idx) = o;
    }
  }
}

// ---------------- column attention: one block per (w, H) ----------------
// In-register softmax: after QK^T the 16 lanes sharing q hold the same row,
// so row-reduce = 7 in-register ops over j + shfl_xor butterfly over l-bits.
__global__ __launch_bounds__(256) void col_attn(const unsigned short* __restrict__ C,
                                                unsigned short* __restrict__ O) {
  __shared__ unsigned short Sp[128 * 136];  // normalized P (bf16)
  __shared__ unsigned short Vt[64 * 136];   // V^T
  const int w = blockIdx.x, H = blockIdx.y;
  const int tid = threadIdx.x, wave = tid >> 6, lane = tid & 63;
  const int q = lane >> 4, l = lane & 15;
  const size_t slab = (size_t)(w * 8 + H) * 8192;  // 128x64
  const unsigned short* Qs = C + slab;
  const unsigned short* Ks = C + 16777216 + slab;
  const unsigned short* Vs = C + 33554432 + slab;
  // stage V^T: Vt[d][j] = V[j][d]
  for (int u = tid; u < 1024; u += 256) {
    const int j = u >> 3, db = u & 7;
    s16x8 v = *(const s16x8*)(Vs + j * 64 + db * 8);
#pragma unroll
    for (int t = 0; t < 8; ++t) Vt[(db * 8 + t) * 136 + j] = v[t];
  }
  // S = q k^T * scale; wave handles 32 rows
  const int m0 = wave * 32;
  f32x4 acc[2][8] = {};
#pragma unroll
  for (int ks = 0; ks < 2; ++ks) {
    const int kk = ks * 32 + q * 8;
    s16x8 a[2], b[8];
#pragma unroll
    for (int i = 0; i < 2; ++i) a[i] = *(const s16x8*)(Qs + (m0 + i * 16 + l) * 64 + kk);
#pragma unroll
    for (int j = 0; j < 8; ++j) b[j] = *(const s16x8*)(Ks + (j * 16 + l) * 64 + kk);
#pragma unroll
    for (int i = 0; i < 2; ++i)
#pragma unroll
      for (int j = 0; j < 8; ++j) acc[i][j] = MFMA16(a[i], b[j], acc[i][j]);
  }
  // in-register softmax per owned row; write normalized bf16 P to LDS
#pragma unroll
  for (int i = 0; i < 2; ++i)
#pragma unroll
    for (int r = 0; r < 4; ++r) {
      float v[8];
#pragma unroll
      for (int j = 0; j < 8; ++j) v[j] = acc[i][j][r] * 0.125f;
      float mx = fmaxf(fmaxf(fmaxf(v[0], v[1]), fmaxf(v[2], v[3])),
                       fmaxf(fmaxf(v[4], v[5]), fmaxf(v[6], v[7])));
      mx = fmaxf(mx, __shfl_xor(mx, 1));
      mx = fmaxf(mx, __shfl_xor(mx, 2));
      mx = fmaxf(mx, __shfl_xor(mx, 4));
      mx = fmaxf(mx, __shfl_xor(mx, 8));
      float s = 0.f;
#pragma unroll
      for (int j = 0; j < 8; ++j) { v[j] = __expf(v[j] - mx); s += v[j]; }
      s += __shfl_xor(s, 1);
      s += __shfl_xor(s, 2);
      s += __shfl_xor(s, 4);
      s += __shfl_xor(s, 8);
      const float inv = 1.0f / s;
      const int row = m0 + i * 16 + q * 4 + r;
#pragma unroll
      for (int j = 0; j < 8; ++j) Sp[row * 136 + j * 16 + l] = f2b(v[j] * inv);
    }
  __syncthreads();  // covers V^T staging and P visibility
  // O = P @ V
  f32x4 o[2][4] = {};
#pragma unroll
  for (int ks = 0; ks < 4; ++ks) {
    const int kk = ks * 32 + q * 8;
    s16x8 a[2], b[4];
#pragma unroll
    for (int i = 0; i < 2; ++i) a[i] = *(const s16x8*)(&Sp[(m0 + i * 16 + l) * 136 + kk]);
#pragma unroll
    for (int j = 0; j < 4; ++j) b[j] = *(const s16x8*)(&Vt[(j * 16 + l) * 136 + kk]);
#pragma unroll
    for (int i = 0; i < 2; ++i)
#pragma unroll
      for (int j = 0; j < 4; ++j) o[i][j] = MFMA16(a[i], b[j], o[i][j]);
  }
#pragma unroll
  for (int i = 0; i < 2; ++i)
#pragma unroll
    for (int j = 0; j < 4; ++j)
#pragma unroll
      for (int r = 0; r < 4; ++r) {
        const int row = m0 + i * 16 + q * 4 + r;  // seq pos (h index)
        const int d = j * 16 + l;
        O[(size_t)(row * 256 + w) * 1024 + H * 64 + d] = f2b(o[i][j][r]);
      }
}

// ---------------- tied row attention dots, split-K over 8 chunks of 16 rows ----------------
__global__ __launch_bounds__(256) void row_dots(const unsigned short* __restrict__ C,
                                                float* __restrict__ dp) {
  const int H = blockIdx.z;
  const int r0 = blockIdx.y * 16;
  const int ti = blockIdx.x & 1, tj = blockIdx.x >> 1;
  const int tid = threadIdx.x, wave = tid >> 6, lane = tid & 63;
  const int q = lane >> 4, l = lane & 15;
  const int m0 = ti * 128 + (wave >> 1) * 64;
  const int n0 = tj * 128 + (wave & 1) * 64;
  const unsigned short* Qh = C;
  const unsigned short* Kh = C + 16777216;
  f32x4 acc[4][4] = {};
  for (int ks = 0; ks < 32; ++ks) {
    const int k = ks * 32 + q * 8;
    const int rr = r0 + (k >> 6), d = k & 63;
    const size_t slab = (size_t)(rr * 8 + H) * 16384;  // 256x64
    s16x8 a[4], b[4];
#pragma unroll
    for (int i = 0; i < 4; ++i) a[i] = *(const s16x8*)(Qh + slab + (m0 + i * 16 + l) * 64 + d);
#pragma unroll
    for (int j = 0; j < 4; ++j) b[j] = *(const s16x8*)(Kh + slab + (n0 + j * 16 + l) * 64 + d);
#pragma unroll
    for (int i = 0; i < 4; ++i)
#pragma unroll
      for (int j = 0; j < 4; ++j) acc[i][j] = MFMA16(a[i], b[j], acc[i][j]);
  }
  float* outp = dp + ((size_t)blockIdx.y * 8 + H) * 65536;
#pragma unroll
  for (int i = 0; i < 4; ++i)
#pragma unroll
    for (int j = 0; j < 4; ++j)
#pragma unroll
      for (int r = 0; r < 4; ++r)
        outp[(size_t)(m0 + i * 16 + q * 4 + r) * 256 + n0 + j * 16 + l] = acc[i][j][r];
}

__global__ __launch_bounds__(256) void row_softmax(const float* __restrict__ dp,
                                                   unsigned short* __restrict__ attn) {
  const int row = blockIdx.x;  // H*256 + i
  const int H = row >> 8, i = row & 255;
  const int t = threadIdx.x, wave = t >> 6, lane = t & 63;
  __shared__ float red[8];
  float v = 0.f;
#pragma unroll
  for (int c = 0; c < 8; ++c) v += dp[((size_t)c * 8 + H) * 65536 + (size_t)i * 256 + t];
  v *= 1.1048543456e-2f;  // 0.125 / sqrt(128)
  float m = v;
  for (int o = 32; o > 0; o >>= 1) m = fmaxf(m, __shfl_xor(m, o, 64));
  if (lane == 0) red[wave] = m;
  __syncthreads();
  const float M = fmaxf(fmaxf(red[0], red[1]), fmaxf(red[2], red[3]));
  const float e = __expf(v - M);
  float s = e;
  for (int o = 32; o > 0; o >>= 1) s += __shfl_xor(s, o, 64);
  if (lane == 0) red[4 + wave] = s;
  __syncthreads();
  const float S = red[4] + red[5] + red[6] + red[7];
  attn[(size_t)row * 256 + t] = f2b(e / S);
}

// ---------------- row attention PV: one block per (r, H) ----------------
__global__ __launch_bounds__(256) void row_pv(const unsigned short* __restrict__ C,
                                              const unsigned short* __restrict__ attn,
                                              unsigned short* __restrict__ O) {
  __shared__ unsigned short Vt[64 * 264];
  const int r = blockIdx.x, H = blockIdx.y;
  const int tid = threadIdx.x, wave = tid >> 6, lane = tid & 63;
  const int q = lane >> 4, l = lane & 15;
  const unsigned short* Vs = C + 33554432 + (size_t)(r * 8 + H) * 16384;
  for (int u = tid; u < 2048; u += 256) {
    const int j = u >> 3, db = u & 7;
    s16x8 v = *(const s16x8*)(Vs + j * 64 + db * 8);
#pragma unroll
    for (int t = 0; t < 8; ++t) Vt[(db * 8 + t) * 264 + j] = v[t];
  }
  __syncthreads();
  const unsigned short* A = attn + (size_t)H * 65536;
  const int m0 = wave * 64;
  f32x4 acc[4][4] = {};
#pragma unroll
  for (int ks = 0; ks < 8; ++ks) {
    const int kk = ks * 32 + q * 8;
    s16x8 a[4], b[4];
#pragma unroll
    for (int i = 0; i < 4; ++i) a[i] = *(const s16x8*)(A + (size_t)(m0 + i * 16 + l) * 256 + kk);
#pragma unroll
    for (int j = 0; j < 4; ++j) b[j] = *(const s16x8*)(&Vt[(j * 16 + l) * 264 + kk]);
#pragma unroll
    for (int i = 0; i < 4; ++i)
#pragma unroll
      for (int j = 0; j < 4; ++j) acc[i][j] = MFMA16(a[i], b[j], acc[i][j]);
  }
#pragma unroll
  for (int i = 0; i < 4; ++i)
#pragma unroll
    for (int j = 0; j < 4; ++j)
#pragma unroll
      for (int rr = 0; rr < 4; ++rr) {
        const int iw = m0 + i * 16 + q * 4 + rr;  // w index
        const int d = j * 16 + l;
        O[(size_t)(r * 256 + iw) * 1024 + 512 + H * 64 + d] = f2b(acc[i][j][rr]);
      }
}

// ---------------- output projection with LDS staging: out = Ocat(32768x1024) @ W2 + bias ----------------
// MFMA operands SWAPPED: lane holds 4 consecutive cols for fixed row -> float4 stores.
__global__ __launch_bounds__(256) void out_proj(const unsigned short* __restrict__ O,
                                                const unsigned short* __restrict__ W2T,
                                                const float* __restrict__ bw,
                                                const float* __restrict__ bh,
                                                float* __restrict__ out) {
  __shared__ unsigned short As[128 * 32];
  __shared__ unsigned short Bs[128 * 32];
  const int tid = threadIdx.x, wave = tid >> 6, lane = tid & 63;
  const int q = lane >> 4, l = lane & 15;
  const int m0 = blockIdx.x * 128;
  const int n0 = blockIdx.y * 128;
  const int mt = (wave >> 1) * 64;
  const int nt = (wave & 1) * 64;
  const char* Ob = (const char*)O;
  const char* Wb = (const char*)W2T;
  const int srow = wave * 32 + (lane >> 2);
  const int sboff = (lane & 3) * 16;
  char* AsB = (char*)As;
  char* BsB = (char*)Bs;
  f32x4 acc[4][4] = {};
  for (int ks = 0; ks < 32; ++ks) {
    const int kb = ks * 64;  // byte offset within 2048-B row
    gld_lds16(Ob + (size_t)(m0 + srow) * 2048 + kb + sboff, AsB + wave * 2048);
    gld_lds16(Ob + (size_t)(m0 + srow + 16) * 2048 + kb + sboff, AsB + wave * 2048 + 1024);
    gld_lds16(Wb + (size_t)(n0 + srow) * 2048 + kb + sboff, BsB + wave * 2048);
    gld_lds16(Wb + (size_t)(n0 + srow + 16) * 2048 + kb + sboff, BsB + wave * 2048 + 1024);
    __syncthreads();
    s16x8 a[4], b[4];
#pragma unroll
    for (int i = 0; i < 4; ++i) a[i] = *(const s16x8*)(&As[(mt + i * 16 + l) * 32 + q * 8]);
#pragma unroll
    for (int j = 0; j < 4; ++j) b[j] = *(const s16x8*)(&Bs[(nt + j * 16 + l) * 32 + q * 8]);
#pragma unroll
    for (int i = 0; i < 4; ++i)
#pragma unroll
      for (int j = 0; j < 4; ++j) acc[i][j] = MFMA16(b[j], a[i], acc[i][j]);  // swapped: D^T
    __syncthreads();
  }
#pragma unroll
  for (int i = 0; i < 4; ++i) {
    const int m = m0 + mt + i * 16 + l;
#pragma unroll
    for (int j = 0; j < 4; ++j) {
      const int col = n0 + nt + j * 16 + q * 4;
      const float4 bwv = *(const float4*)(bw + col);
      const float4 bhv = *(const float4*)(bh + col);
      float4 ov;
      ov.x = acc[i][j][0] + bwv.x + bhv.x;
      ov.y = acc[i][j][1] + bwv.y + bhv.y;
      ov.z = acc[i][j][2] + bwv.z + bhv.z;
      ov.w = acc[i][j][3] + bwv.w + bhv.w;
      *(float4*)(out + (size_t)m * 256 + col) = ov;
    }
  }
}

extern "C" void kernel_launch(void* const* d_in, const int* in_sizes, int n_in,
                              void* d_out, int out_size, void* d_ws, size_t ws_size,
                              hipStream_t stream) {
  const float* x    = (const float*)d_in[0];
  const float* wq   = (const float*)d_in[1];
  const float* wkv  = (const float*)d_in[2];
  const float* wout = (const float*)d_in[3];
  const float* bw   = (const float*)d_in[4];
  const float* hq   = (const float*)d_in[5];
  const float* hkv  = (const float*)d_in[6];
  const float* hout = (const float*)d_in[7];
  const float* bh   = (const float*)d_in[8];
  float* out = (float*)d_out;

  char* ws = (char*)d_ws;
  unsigned short* x_bf  = (unsigned short*)(ws);               // 16 MB
  unsigned short* WcatT = (unsigned short*)(ws + 16777216);    // 1.5 MB
  unsigned short* W2T   = (unsigned short*)(ws + 18350080);    // 0.5 MB
  float*          dp    = (float*)(ws + 18874368);             // 16 MB
  unsigned short* attn  = (unsigned short*)(ws + 35651584);    // 1 MB
  unsigned short* Ocat  = (unsigned short*)(ws + 36700160);    // 64 MB
  unsigned short* Cproj = (unsigned short*)(ws + 103809024);   // 96 MB (reused per branch)

  cvt_x<<<8192, 256, 0, stream>>>(x, x_bf);
  build_wt<<<3072, 256, 0, stream>>>(wq, wkv, hq, hkv, WcatT);
  build_w2t<<<256, 256, 0, stream>>>(wout, hout, W2T);

  // w-branch (column attention)
  gemm_qkv<<<dim3(12, 256), 256, 0, stream>>>(x_bf, WcatT, Cproj, 0);
  col_attn<<<dim3(256, 8), 256, 0, stream>>>(Cproj, Ocat);
  // h-branch (tied row attention), reuses Cproj
  gemm_qkv<<<dim3(12, 256), 256, 0, stream>>>(x_bf, WcatT + 1536 * 256, Cproj, 1);
  row_dots<<<dim3(4, 8, 8), 256, 0, stream>>>(Cproj, dp);
  row_softmax<<<2048, 256, 0, stream>>>(dp, attn);
  row_pv<<<dim3(128, 8), 256, 0, stream>>>(Cproj, attn, Ocat);
  out_proj<<<dim3(256, 2), 256, 0, stream>>>(Ocat, W2T, bw, bh, out);
}

// Round 10
// 343.992 us; speedup vs baseline: 1.4422x; 1.1303x over previous
//
#include <hip/hip_runtime.h>

typedef short s16x8 __attribute__((ext_vector_type(8)));
typedef float f32x4 __attribute__((ext_vector_type(4)));

#define MFMA16(a, b, c) __builtin_amdgcn_mfma_f32_16x16x32_bf16((a), (b), (c), 0, 0, 0)

__device__ __forceinline__ unsigned short f2b(float f) {
  union { float f; unsigned int u; } v; v.f = f;
  unsigned int u = v.u;
  unsigned int r = (u + 0x7fffu + ((u >> 16) & 1u)) >> 16;  // RNE
  return (unsigned short)r;
}
__device__ __forceinline__ float b2f(unsigned short b) {
  union { unsigned int u; float f; } v; v.u = ((unsigned int)b) << 16;
  return v.f;
}

__device__ __forceinline__ void gld_lds16(const void* g, void* l) {
  __builtin_amdgcn_global_load_lds(
      (const __attribute__((address_space(1))) unsigned int*)g,
      (__attribute__((address_space(3))) unsigned int*)l, 16, 0, 0);
}

// ---------------- prep ----------------
__global__ __launch_bounds__(256) void cvt_x(const float* __restrict__ x,
                                             unsigned short* __restrict__ xb) {
  size_t i = ((size_t)blockIdx.x * 256 + threadIdx.x) * 4;
  float4 v = *(const float4*)(x + i);
  ushort4 o;
  o.x = f2b(v.x); o.y = f2b(v.y); o.z = f2b(v.z); o.w = f2b(v.w);
  *(ushort4*)(xb + i) = o;
}

// WcatT[n][k] = W[k][n], n in [0,3072): [wq | wkv | hq | hkv]
__global__ __launch_bounds__(256) void build_wt(const float* __restrict__ wq,
                                                const float* __restrict__ wkv,
                                                const float* __restrict__ hq,
                                                const float* __restrict__ hkv,
                                                unsigned short* __restrict__ WT) {
  const int n = blockIdx.x, k = threadIdx.x;
  float v;
  if (n < 512)       v = wq [(size_t)k * 512  + n];
  else if (n < 1536) v = wkv[(size_t)k * 1024 + (n - 512)];
  else if (n < 2048) v = hq [(size_t)k * 512  + (n - 1536)];
  else               v = hkv[(size_t)k * 1024 + (n - 2048)];
  WT[(size_t)n * 256 + k] = f2b(v);
}

// W2T[n][k] = [wout;hout][k][n], n<256, k<1024
__global__ __launch_bounds__(256) void build_w2t(const float* __restrict__ wout,
                                                 const float* __restrict__ hout,
                                                 unsigned short* __restrict__ W2T) {
  const int n = blockIdx.x;
  for (int k = threadIdx.x; k < 1024; k += 256) {
    const float v = (k < 512) ? wout[(size_t)k * 256 + n] : hout[(size_t)(k - 512) * 256 + n];
    W2T[(size_t)n * 1024 + k] = f2b(v);
  }
}

// ---------------- QKV projection with LDS staging (r1 structure, measured best) ----------
// XCD-chunked block remap: logical = (bid&7)*384 + (bid>>3); n-fastest within logical.
// Each XCD owns a contiguous run of 32 m-panels x 12 n-tiles, so the 12 blocks
// sharing an A-panel are co-resident on ONE XCD -> A-panel staged from L2, X
// fetched once chip-wide. Everything else identical to the measured-best r1 kernel.
// C layout (per part q/k/v of 16777216 elems):
//   branch 0 (col attn): part + ((w*8+H)*128 + h)*64 + d     (slab = 128x64)
//   branch 1 (row attn): part + ((r*8+H)*256 + i)*64 + d     (slab = 256x64)
__global__ __launch_bounds__(256) void gemm_qkv(const unsigned short* __restrict__ X,
                                                const unsigned short* __restrict__ WT,
                                                unsigned short* __restrict__ C,
                                                int branch) {
  __shared__ unsigned short As[128 * 32];
  __shared__ unsigned short Bs[128 * 32];
  const int tid = threadIdx.x, wave = tid >> 6, lane = tid & 63;
  const int q = lane >> 4, l = lane & 15;
  const int logical = (blockIdx.x & 7) * 384 + (blockIdx.x >> 3);  // bijective, 3072%8==0
  const int m0 = (logical / 12) * 128;
  const int n0 = (logical % 12) * 128;
  const int mt = (wave >> 1) * 64;  // wave tile row in block
  const int nt = (wave & 1) * 64;
  const char* Xb = (const char*)X;
  const char* Wb = (const char*)WT;
  const int srow = wave * 32 + (lane >> 2);  // staging row (+16 for second half)
  const int sboff = (lane & 3) * 16;         // byte offset within 64-B row chunk
  char* AsB = (char*)As;
  char* BsB = (char*)Bs;
  f32x4 acc[4][4] = {};
#pragma unroll
  for (int ks = 0; ks < 8; ++ks) {
    const int kb = ks * 64;  // byte offset of k-chunk within 512-B row
    gld_lds16(Xb + (size_t)(m0 + srow) * 512 + kb + sboff, AsB + wave * 2048);
    gld_lds16(Xb + (size_t)(m0 + srow + 16) * 512 + kb + sboff, AsB + wave * 2048 + 1024);
    gld_lds16(Wb + (size_t)(n0 + srow) * 512 + kb + sboff, BsB + wave * 2048);
    gld_lds16(Wb + (size_t)(n0 + srow + 16) * 512 + kb + sboff, BsB + wave * 2048 + 1024);
    __syncthreads();
    s16x8 a[4], b[4];
#pragma unroll
    for (int i = 0; i < 4; ++i) a[i] = *(const s16x8*)(&As[(mt + i * 16 + l) * 32 + q * 8]);
#pragma unroll
    for (int j = 0; j < 4; ++j) b[j] = *(const s16x8*)(&Bs[(nt + j * 16 + l) * 32 + q * 8]);
#pragma unroll
    for (int i = 0; i < 4; ++i)
#pragma unroll
      for (int j = 0; j < 4; ++j) acc[i][j] = MFMA16(a[i], b[j], acc[i][j]);
    __syncthreads();
  }
#pragma unroll
  for (int i = 0; i < 4; ++i)
#pragma unroll
    for (int j = 0; j < 4; ++j) {
      const int col = n0 + nt + j * 16 + l;
      const int part = col >> 9, H = (col & 511) >> 6, d = col & 63;
      unsigned short* base = C + (size_t)part * 16777216;
#pragma unroll
      for (int r = 0; r < 4; ++r) {
        const int m = m0 + mt + i * 16 + q * 4 + r;
        size_t idx;
        if (branch == 0) idx = ((size_t)((m & 255) * 8 + H) * 128 + (m >> 8)) * 64 + d;
        else             idx = ((size_t)((m >> 8) * 8 + H) * 256 + (m & 255)) * 64 + d;
        base[idx] = f2b(acc[i][j][r]);
      }
    }
}

// ---------------- column attention: one block per (w, H) ----------------
// In-register softmax: after QK^T the 16 lanes sharing q hold the same row,
// so row-reduce = 7 in-register ops over j + shfl_xor butterfly over l-bits.
__global__ __launch_bounds__(256) void col_attn(const unsigned short* __restrict__ C,
                                                unsigned short* __restrict__ O) {
  __shared__ unsigned short Sp[128 * 136];  // normalized P (bf16)
  __shared__ unsigned short Vt[64 * 136];   // V^T
  const int w = blockIdx.x, H = blockIdx.y;
  const int tid = threadIdx.x, wave = tid >> 6, lane = tid & 63;
  const int q = lane >> 4, l = lane & 15;
  const size_t slab = (size_t)(w * 8 + H) * 8192;  // 128x64
  const unsigned short* Qs = C + slab;
  const unsigned short* Ks = C + 16777216 + slab;
  const unsigned short* Vs = C + 33554432 + slab;
  // stage V^T: Vt[d][j] = V[j][d]
  for (int u = tid; u < 1024; u += 256) {
    const int j = u >> 3, db = u & 7;
    s16x8 v = *(const s16x8*)(Vs + j * 64 + db * 8);
#pragma unroll
    for (int t = 0; t < 8; ++t) Vt[(db * 8 + t) * 136 + j] = v[t];
  }
  // S = q k^T * scale; wave handles 32 rows
  const int m0 = wave * 32;
  f32x4 acc[2][8] = {};
#pragma unroll
  for (int ks = 0; ks < 2; ++ks) {
    const int kk = ks * 32 + q * 8;
    s16x8 a[2], b[8];
#pragma unroll
    for (int i = 0; i < 2; ++i) a[i] = *(const s16x8*)(Qs + (m0 + i * 16 + l) * 64 + kk);
#pragma unroll
    for (int j = 0; j < 8; ++j) b[j] = *(const s16x8*)(Ks + (j * 16 + l) * 64 + kk);
#pragma unroll
    for (int i = 0; i < 2; ++i)
#pragma unroll
      for (int j = 0; j < 8; ++j) acc[i][j] = MFMA16(a[i], b[j], acc[i][j]);
  }
  // in-register softmax per owned row; write normalized bf16 P to LDS
#pragma unroll
  for (int i = 0; i < 2; ++i)
#pragma unroll
    for (int r = 0; r < 4; ++r) {
      float v[8];
#pragma unroll
      for (int j = 0; j < 8; ++j) v[j] = acc[i][j][r] * 0.125f;
      float mx = fmaxf(fmaxf(fmaxf(v[0], v[1]), fmaxf(v[2], v[3])),
                       fmaxf(fmaxf(v[4], v[5]), fmaxf(v[6], v[7])));
      mx = fmaxf(mx, __shfl_xor(mx, 1));
      mx = fmaxf(mx, __shfl_xor(mx, 2));
      mx = fmaxf(mx, __shfl_xor(mx, 4));
      mx = fmaxf(mx, __shfl_xor(mx, 8));
      float s = 0.f;
#pragma unroll
      for (int j = 0; j < 8; ++j) { v[j] = __expf(v[j] - mx); s += v[j]; }
      s += __shfl_xor(s, 1);
      s += __shfl_xor(s, 2);
      s += __shfl_xor(s, 4);
      s += __shfl_xor(s, 8);
      const float inv = 1.0f / s;
      const int row = m0 + i * 16 + q * 4 + r;
#pragma unroll
      for (int j = 0; j < 8; ++j) Sp[row * 136 + j * 16 + l] = f2b(v[j] * inv);
    }
  __syncthreads();  // covers V^T staging and P visibility
  // O = P @ V
  f32x4 o[2][4] = {};
#pragma unroll
  for (int ks = 0; ks < 4; ++ks) {
    const int kk = ks * 32 + q * 8;
    s16x8 a[2], b[4];
#pragma unroll
    for (int i = 0; i < 2; ++i) a[i] = *(const s16x8*)(&Sp[(m0 + i * 16 + l) * 136 + kk]);
#pragma unroll
    for (int j = 0; j < 4; ++j) b[j] = *(const s16x8*)(&Vt[(j * 16 + l) * 136 + kk]);
#pragma unroll
    for (int i = 0; i < 2; ++i)
#pragma unroll
      for (int j = 0; j < 4; ++j) o[i][j] = MFMA16(a[i], b[j], o[i][j]);
  }
#pragma unroll
  for (int i = 0; i < 2; ++i)
#pragma unroll
    for (int j = 0; j < 4; ++j)
#pragma unroll
      for (int r = 0; r < 4; ++r) {
        const int row = m0 + i * 16 + q * 4 + r;  // seq pos (h index)
        const int d = j * 16 + l;
        O[(size_t)(row * 256 + w) * 1024 + H * 64 + d] = f2b(o[i][j][r]);
      }
}

// ---------------- tied row attention dots, split-K over 8 chunks of 16 rows ----------------
__global__ __launch_bounds__(256) void row_dots(const unsigned short* __restrict__ C,
                                                float* __restrict__ dp) {
  const int H = blockIdx.z;
  const int r0 = blockIdx.y * 16;
  const int ti = blockIdx.x & 1, tj = blockIdx.x >> 1;
  const int tid = threadIdx.x, wave = tid >> 6, lane = tid & 63;
  const int q = lane >> 4, l = lane & 15;
  const int m0 = ti * 128 + (wave >> 1) * 64;
  const int n0 = tj * 128 + (wave & 1) * 64;
  const unsigned short* Qh = C;
  const unsigned short* Kh = C + 16777216;
  f32x4 acc[4][4] = {};
  for (int ks = 0; ks < 32; ++ks) {
    const int k = ks * 32 + q * 8;
    const int rr = r0 + (k >> 6), d = k & 63;
    const size_t slab = (size_t)(rr * 8 + H) * 16384;  // 256x64
    s16x8 a[4], b[4];
#pragma unroll
    for (int i = 0; i < 4; ++i) a[i] = *(const s16x8*)(Qh + slab + (m0 + i * 16 + l) * 64 + d);
#pragma unroll
    for (int j = 0; j < 4; ++j) b[j] = *(const s16x8*)(Kh + slab + (n0 + j * 16 + l) * 64 + d);
#pragma unroll
    for (int i = 0; i < 4; ++i)
#pragma unroll
      for (int j = 0; j < 4; ++j) acc[i][j] = MFMA16(a[i], b[j], acc[i][j]);
  }
  float* outp = dp + ((size_t)blockIdx.y * 8 + H) * 65536;
#pragma unroll
  for (int i = 0; i < 4; ++i)
#pragma unroll
    for (int j = 0; j < 4; ++j)
#pragma unroll
      for (int r = 0; r < 4; ++r)
        outp[(size_t)(m0 + i * 16 + q * 4 + r) * 256 + n0 + j * 16 + l] = acc[i][j][r];
}

__global__ __launch_bounds__(256) void row_softmax(const float* __restrict__ dp,
                                                   unsigned short* __restrict__ attn) {
  const int row = blockIdx.x;  // H*256 + i
  const int H = row >> 8, i = row & 255;
  const int t = threadIdx.x, wave = t >> 6, lane = t & 63;
  __shared__ float red[8];
  float v = 0.f;
#pragma unroll
  for (int c = 0; c < 8; ++c) v += dp[((size_t)c * 8 + H) * 65536 + (size_t)i * 256 + t];
  v *= 1.1048543456e-2f;  // 0.125 / sqrt(128)
  float m = v;
  for (int o = 32; o > 0; o >>= 1) m = fmaxf(m, __shfl_xor(m, o, 64));
  if (lane == 0) red[wave] = m;
  __syncthreads();
  const float M = fmaxf(fmaxf(red[0], red[1]), fmaxf(red[2], red[3]));
  const float e = __expf(v - M);
  float s = e;
  for (int o = 32; o > 0; o >>= 1) s += __shfl_xor(s, o, 64);
  if (lane == 0) red[4 + wave] = s;
  __syncthreads();
  const float S = red[4] + red[5] + red[6] + red[7];
  attn[(size_t)row * 256 + t] = f2b(e / S);
}

// ---------------- row attention PV: one block per (r, H) ----------------
__global__ __launch_bounds__(256) void row_pv(const unsigned short* __restrict__ C,
                                              const unsigned short* __restrict__ attn,
                                              unsigned short* __restrict__ O) {
  __shared__ unsigned short Vt[64 * 264];
  const int r = blockIdx.x, H = blockIdx.y;
  const int tid = threadIdx.x, wave = tid >> 6, lane = tid & 63;
  const int q = lane >> 4, l = lane & 15;
  const unsigned short* Vs = C + 33554432 + (size_t)(r * 8 + H) * 16384;
  for (int u = tid; u < 2048; u += 256) {
    const int j = u >> 3, db = u & 7;
    s16x8 v = *(const s16x8*)(Vs + j * 64 + db * 8);
#pragma unroll
    for (int t = 0; t < 8; ++t) Vt[(db * 8 + t) * 264 + j] = v[t];
  }
  __syncthreads();
  const unsigned short* A = attn + (size_t)H * 65536;
  const int m0 = wave * 64;
  f32x4 acc[4][4] = {};
#pragma unroll
  for (int ks = 0; ks < 8; ++ks) {
    const int kk = ks * 32 + q * 8;
    s16x8 a[4], b[4];
#pragma unroll
    for (int i = 0; i < 4; ++i) a[i] = *(const s16x8*)(A + (size_t)(m0 + i * 16 + l) * 256 + kk);
#pragma unroll
    for (int j = 0; j < 4; ++j) b[j] = *(const s16x8*)(&Vt[(j * 16 + l) * 264 + kk]);
#pragma unroll
    for (int i = 0; i < 4; ++i)
#pragma unroll
      for (int j = 0; j < 4; ++j) acc[i][j] = MFMA16(a[i], b[j], acc[i][j]);
  }
#pragma unroll
  for (int i = 0; i < 4; ++i)
#pragma unroll
    for (int j = 0; j < 4; ++j)
#pragma unroll
      for (int rr = 0; rr < 4; ++rr) {
        const int iw = m0 + i * 16 + q * 4 + rr;  // w index
        const int d = j * 16 + l;
        O[(size_t)(r * 256 + iw) * 1024 + 512 + H * 64 + d] = f2b(acc[i][j][rr]);
      }
}

// ---------------- output projection with LDS staging: out = Ocat(32768x1024) @ W2 + bias ----------------
__global__ __launch_bounds__(256) void out_proj(const unsigned short* __restrict__ O,
                                                const unsigned short* __restrict__ W2T,
                                                const float* __restrict__ bw,
                                                const float* __restrict__ bh,
                                                float* __restrict__ out) {
  __shared__ unsigned short As[128 * 32];
  __shared__ unsigned short Bs[128 * 32];
  const int tid = threadIdx.x, wave = tid >> 6, lane = tid & 63;
  const int q = lane >> 4, l = lane & 15;
  const int m0 = blockIdx.x * 128;
  const int n0 = blockIdx.y * 128;
  const int mt = (wave >> 1) * 64;
  const int nt = (wave & 1) * 64;
  const char* Ob = (const char*)O;
  const char* Wb = (const char*)W2T;
  const int srow = wave * 32 + (lane >> 2);
  const int sboff = (lane & 3) * 16;
  char* AsB = (char*)As;
  char* BsB = (char*)Bs;
  f32x4 acc[4][4] = {};
  for (int ks = 0; ks < 32; ++ks) {
    const int kb = ks * 64;  // byte offset within 2048-B row
    gld_lds16(Ob + (size_t)(m0 + srow) * 2048 + kb + sboff, AsB + wave * 2048);
    gld_lds16(Ob + (size_t)(m0 + srow + 16) * 2048 + kb + sboff, AsB + wave * 2048 + 1024);
    gld_lds16(Wb + (size_t)(n0 + srow) * 2048 + kb + sboff, BsB + wave * 2048);
    gld_lds16(Wb + (size_t)(n0 + srow + 16) * 2048 + kb + sboff, BsB + wave * 2048 + 1024);
    __syncthreads();
    s16x8 a[4], b[4];
#pragma unroll
    for (int i = 0; i < 4; ++i) a[i] = *(const s16x8*)(&As[(mt + i * 16 + l) * 32 + q * 8]);
#pragma unroll
    for (int j = 0; j < 4; ++j) b[j] = *(const s16x8*)(&Bs[(nt + j * 16 + l) * 32 + q * 8]);
#pragma unroll
    for (int i = 0; i < 4; ++i)
#pragma unroll
      for (int j = 0; j < 4; ++j) acc[i][j] = MFMA16(a[i], b[j], acc[i][j]);
    __syncthreads();
  }
#pragma unroll
  for (int i = 0; i < 4; ++i)
#pragma unroll
    for (int j = 0; j < 4; ++j) {
      const int col = n0 + nt + j * 16 + l;
      const float bias = bw[col] + bh[col];
#pragma unroll
      for (int r = 0; r < 4; ++r)
        out[(size_t)(m0 + mt + i * 16 + q * 4 + r) * 256 + col] = acc[i][j][r] + bias;
    }
}

extern "C" void kernel_launch(void* const* d_in, const int* in_sizes, int n_in,
                              void* d_out, int out_size, void* d_ws, size_t ws_size,
                              hipStream_t stream) {
  const float* x    = (const float*)d_in[0];
  const float* wq   = (const float*)d_in[1];
  const float* wkv  = (const float*)d_in[2];
  const float* wout = (const float*)d_in[3];
  const float* bw   = (const float*)d_in[4];
  const float* hq   = (const float*)d_in[5];
  const float* hkv  = (const float*)d_in[6];
  const float* hout = (const float*)d_in[7];
  const float* bh   = (const float*)d_in[8];
  float* out = (float*)d_out;

  char* ws = (char*)d_ws;
  unsigned short* x_bf  = (unsigned short*)(ws);               // 16 MB
  unsigned short* WcatT = (unsigned short*)(ws + 16777216);    // 1.5 MB
  unsigned short* W2T   = (unsigned short*)(ws + 18350080);    // 0.5 MB
  float*          dp    = (float*)(ws + 18874368);             // 16 MB
  unsigned short* attn  = (unsigned short*)(ws + 35651584);    // 1 MB
  unsigned short* Ocat  = (unsigned short*)(ws + 36700160);    // 64 MB
  unsigned short* Cproj = (unsigned short*)(ws + 103809024);   // 96 MB (reused per branch)

  cvt_x<<<8192, 256, 0, stream>>>(x, x_bf);
  build_wt<<<3072, 256, 0, stream>>>(wq, wkv, hq, hkv, WcatT);
  build_w2t<<<256, 256, 0, stream>>>(wout, hout, W2T);

  // w-branch (column attention)
  gemm_qkv<<<3072, 256, 0, stream>>>(x_bf, WcatT, Cproj, 0);
  col_attn<<<dim3(256, 8), 256, 0, stream>>>(Cproj, Ocat);
  // h-branch (tied row attention), reuses Cproj
  gemm_qkv<<<3072, 256, 0, stream>>>(x_bf, WcatT + 1536 * 256, Cproj, 1);
  row_dots<<<dim3(4, 8, 8), 256, 0, stream>>>(Cproj, dp);
  row_softmax<<<2048, 256, 0, stream>>>(dp, attn);
  row_pv<<<dim3(128, 8), 256, 0, stream>>>(Cproj, attn, Ocat);
  out_proj<<<dim3(256, 2), 256, 0, stream>>>(Ocat, W2T, bw, bh, out);
}